// Round 2
// baseline (176.225 us; speedup 1.0000x reference)
//
#include <hip/hip_runtime.h>
#include <hip/hip_bf16.h>
#include <math.h>

#define NCAP 10
#define DCAP 16
#define DIN  128
#define NPOS 4096
#define NB   64

// ---------------------------------------------------------------------------
// ws layout (floats):
//   partial : [64][16][128]  @ 0        (per-chunk partial column sums of u)
//   wbuf    : [64][10][128]  @ 131072   (w = W_n @ v, per (b,n))
//   t1      : [64][10][128]  @ 212992   (sum_i c*u, routing iter 2)
//   t2      : [64][10][128]  @ 294912   (routing iter 3)
// ---------------------------------------------------------------------------

// Pass A: per-batch column sum of u, two-level (block partials, no atomics).
__global__ __launch_bounds__(256) void caps_sum(const float* __restrict__ u,
                                                float* __restrict__ partial) {
    const int b = blockIdx.x;
    const int chunk = blockIdx.y;          // 16 chunks of 256 positions
    const int t = threadIdx.x;
    const int v4 = t & 31;                 // float4 column (32 * 4 = 128 dims)
    const int prow = t >> 5;               // 8 position streams
    const float4* up = (const float4*)u;
    const size_t posbase = (size_t)b * NPOS + chunk * 256;

    float4 acc = make_float4(0.f, 0.f, 0.f, 0.f);
    for (int j = 0; j < 32; ++j) {
        float4 x = up[(posbase + prow + j * 8) * 32 + v4];
        acc.x += x.x; acc.y += x.y; acc.z += x.z; acc.w += x.w;
    }
    __shared__ float4 red[8][32];
    red[prow][v4] = acc;
    __syncthreads();
    if (t < 32) {
        float4 s = red[0][t];
        for (int r = 1; r < 8; ++r) {
            s.x += red[r][t].x; s.y += red[r][t].y;
            s.z += red[r][t].z; s.w += red[r][t].w;
        }
        ((float4*)partial)[((size_t)b * 16 + chunk) * 32 + t] = s;
    }
}

// Small per-(b,n) kernel: s -> squash -> v, then w = W_n @ v (or final output).
// MODE 0: src = partial (reduce 16 chunks, scale by 1/10), dst = wbuf
// MODE 1: src = t (accumulated c*u),                        dst = wbuf
// MODE 2: src = t,                                          dst = out [64][10][16]
template <int MODE>
__global__ __launch_bounds__(128) void caps_small(const float* __restrict__ src,
                                                  const float* __restrict__ W,
                                                  float* __restrict__ dst) {
    const int b = blockIdx.x / NCAP;
    const int n = blockIdx.x % NCAP;
    const int t = threadIdx.x;             // 128 threads, t == din index

    __shared__ float xv[DIN];
    __shared__ float vv[DCAP];

    if (MODE == 0) {
        float a = 0.f;
        for (int c = 0; c < 16; ++c)
            a += src[(size_t)(b * 16 + c) * DIN + t];
        xv[t] = a;
    } else {
        xv[t] = src[(size_t)(b * NCAP + n) * DIN + t];
    }
    __syncthreads();

    if (t < DCAP) {
        float sv = 0.f;
        for (int d = 0; d < DIN; ++d)
            sv = fmaf(xv[d], W[d * (NCAP * DCAP) + n * DCAP + t], sv);
        if (MODE == 0) sv *= 0.1f;         // softmax of zeros over 10 capsules
        // squash over the 16 dims (lanes 0..15 of wave 0)
        float nq = sv * sv;
        #pragma unroll
        for (int mm = 8; mm >= 1; mm >>= 1) nq += __shfl_xor(nq, mm, 16);
        nq += 1e-7f;
        const float coeff = sqrtf(nq) / (1.0f + nq);
        const float v = coeff * sv;
        if (MODE == 2)
            dst[(size_t)(b * NCAP + n) * DCAP + t] = v;
        else
            vv[t] = v;
    }
    if (MODE != 2) {
        __syncthreads();
        float wd = 0.f;
        #pragma unroll
        for (int dd = 0; dd < DCAP; ++dd)
            wd = fmaf(W[t * (NCAP * DCAP) + n * DCAP + dd], vv[dd], wd);
        dst[(size_t)(b * NCAP + n) * DIN + t] = wd;
    }
}

// Routing pass: per position compute 10 logits u.w_n, softmax over n,
// then accumulate t[b][n][:] += c[n] * u[b][i][:].
// Each wave owns a tile of 64 positions; phase 1 lane-owns-position,
// phase 2 lane-owns-dim with shfl broadcast of c. w reads are wave-uniform
// -> compiler emits s_load (scalar cache), no LDS in the hot loop.
__global__ __launch_bounds__(256) void caps_route(const float* __restrict__ u,
                                                  const float* __restrict__ wsrc,
                                                  float* __restrict__ tdst) {
    const int b = blockIdx.x;
    const int chunk = blockIdx.y;          // 16
    const int wave = threadIdx.x >> 6;     // 4 waves
    const int lane = threadIdx.x & 63;
    const int tile = chunk * 4 + wave;     // 64 tiles of 64 positions
    const int pos0 = tile * 64;
    const float* wb = wsrc + (size_t)b * (NCAP * DIN);

    // ---- phase 1: logits + softmax (lane owns position pos0+lane) ----
    const float4* up = (const float4*)(u + ((size_t)b * NPOS + pos0 + lane) * DIN);
    float lg[NCAP];
    #pragma unroll
    for (int n = 0; n < NCAP; ++n) lg[n] = 0.f;
    #pragma unroll 4
    for (int k = 0; k < DIN / 4; ++k) {
        const float4 u4 = up[k];
        #pragma unroll
        for (int n = 0; n < NCAP; ++n) {
            const float4 w4 = ((const float4*)(wb + n * DIN))[k];  // uniform -> s_load
            lg[n] = fmaf(u4.x, w4.x,
                    fmaf(u4.y, w4.y,
                    fmaf(u4.z, w4.z,
                    fmaf(u4.w, w4.w, lg[n]))));
        }
    }
    float m = lg[0];
    #pragma unroll
    for (int n = 1; n < NCAP; ++n) m = fmaxf(m, lg[n]);
    float c[NCAP];
    float ssum = 0.f;
    #pragma unroll
    for (int n = 0; n < NCAP; ++n) { c[n] = __expf(lg[n] - m); ssum += c[n]; }
    const float inv = 1.0f / ssum;
    #pragma unroll
    for (int n = 0; n < NCAP; ++n) c[n] *= inv;

    // ---- phase 2: accumulate over this wave's 64 positions ----
    const float* ub = u + ((size_t)b * NPOS + pos0) * DIN;
    float acc0[NCAP], acc1[NCAP];
    #pragma unroll
    for (int n = 0; n < NCAP; ++n) { acc0[n] = 0.f; acc1[n] = 0.f; }
    for (int p = 0; p < 64; ++p) {
        const float u0 = ub[p * DIN + lane];        // coalesced, L1/L2-hot
        const float u1 = ub[p * DIN + lane + 64];
        #pragma unroll
        for (int n = 0; n < NCAP; ++n) {
            const float cp = __shfl(c[n], p, 64);
            acc0[n] = fmaf(cp, u0, acc0[n]);
            acc1[n] = fmaf(cp, u1, acc1[n]);
        }
    }
    float* tb = tdst + (size_t)b * (NCAP * DIN);
    #pragma unroll
    for (int n = 0; n < NCAP; ++n) {
        atomicAdd(tb + n * DIN + lane, acc0[n]);
        atomicAdd(tb + n * DIN + lane + 64, acc1[n]);
    }
}

extern "C" void kernel_launch(void* const* d_in, const int* in_sizes, int n_in,
                              void* d_out, int out_size, void* d_ws, size_t ws_size,
                              hipStream_t stream) {
    const float* u = (const float*)d_in[0];   // [64][4096][128]
    const float* W = (const float*)d_in[1];   // [128][160]
    float* out = (float*)d_out;               // [64][10][16]
    float* ws = (float*)d_ws;

    float* partial = ws;                      // 131072 floats
    float* wbuf    = ws + 131072;             // 81920 floats
    float* t1      = ws + 212992;             // 81920 floats
    float* t2      = ws + 294912;             // 81920 floats

    // t1/t2 are accumulated with atomics -> zero them (adjacent regions).
    hipMemsetAsync(t1, 0, (size_t)2 * 81920 * sizeof(float), stream);

    caps_sum<<<dim3(NB, 16), 256, 0, stream>>>(u, partial);
    caps_small<0><<<NB * NCAP, 128, 0, stream>>>(partial, W, wbuf);   // v1 -> w1
    caps_route<<<dim3(NB, 16), 256, 0, stream>>>(u, wbuf, t1);        // iter 2 acc
    caps_small<1><<<NB * NCAP, 128, 0, stream>>>(t1, W, wbuf);        // v2 -> w2
    caps_route<<<dim3(NB, 16), 256, 0, stream>>>(u, wbuf, t2);        // iter 3 acc
    caps_small<2><<<NB * NCAP, 128, 0, stream>>>(t2, W, out);         // v3 -> out
}

// Round 4
// 171.522 us; speedup vs baseline: 1.0274x; 1.0274x over previous
//
#include <hip/hip_runtime.h>
#include <hip/hip_bf16.h>
#include <math.h>

#define NCAP 10
#define DCAP 16
#define DIN  128
#define NPOS 4096
#define NB   64

// ---------------------------------------------------------------------------
// ws layout (floats):
//   partial : [64][16][128]      @ 0        (per-chunk partial column sums of u)
//   wbuf    : [64][10][128]      @ 131072   (w = W_n @ v, per (b,n))
//   pws     : [64][16][10][128]  @ 212992   (per-chunk partial c*u sums, reused
//                                            by both routing passes)
// No memset needed: every ws element is written before it is read.
// ---------------------------------------------------------------------------

// Pass A: per-batch column sum of u, two-level (block partials, no atomics).
__global__ __launch_bounds__(256) void caps_sum(const float* __restrict__ u,
                                                float* __restrict__ partial) {
    const int b = blockIdx.x;
    const int chunk = blockIdx.y;          // 16 chunks of 256 positions
    const int t = threadIdx.x;
    const int v4 = t & 31;                 // float4 column (32 * 4 = 128 dims)
    const int prow = t >> 5;               // 8 position streams
    const float4* up = (const float4*)u;
    const size_t posbase = (size_t)b * NPOS + chunk * 256;

    float4 acc = make_float4(0.f, 0.f, 0.f, 0.f);
    for (int j = 0; j < 32; ++j) {
        float4 x = up[(posbase + prow + j * 8) * 32 + v4];
        acc.x += x.x; acc.y += x.y; acc.z += x.z; acc.w += x.w;
    }
    __shared__ float4 red[8][32];
    red[prow][v4] = acc;
    __syncthreads();
    if (t < 32) {
        float4 s = red[0][t];
        for (int r = 1; r < 8; ++r) {
            s.x += red[r][t].x; s.y += red[r][t].y;
            s.z += red[r][t].z; s.w += red[r][t].w;
        }
        ((float4*)partial)[((size_t)b * 16 + chunk) * 32 + t] = s;
    }
}

// Small per-(b,n) kernel: reduce chunk partials -> s -> squash -> v,
// then w = W_n @ v (or final output).
// MODE 0: src = partial [64][16][128] (scale by 1/10),     dst = wbuf
// MODE 1: src = pws [64][16][10][128],                     dst = wbuf
// MODE 2: src = pws,                                       dst = out [64][10][16]
template <int MODE>
__global__ __launch_bounds__(128) void caps_small(const float* __restrict__ src,
                                                  const float* __restrict__ W,
                                                  float* __restrict__ dst) {
    const int b = blockIdx.x / NCAP;
    const int n = blockIdx.x % NCAP;
    const int t = threadIdx.x;             // 128 threads, t == din index

    __shared__ float xv[DIN];
    __shared__ float vv[DCAP];

    float a = 0.f;
    if (MODE == 0) {
        #pragma unroll 4
        for (int c = 0; c < 16; ++c)
            a += src[(size_t)(b * 16 + c) * DIN + t];
    } else {
        #pragma unroll 4
        for (int c = 0; c < 16; ++c)
            a += src[((size_t)(b * 16 + c) * NCAP + n) * DIN + t];
    }
    xv[t] = a;
    __syncthreads();

    if (t < DCAP) {
        float sv = 0.f;
        for (int d = 0; d < DIN; ++d)
            sv = fmaf(xv[d], W[d * (NCAP * DCAP) + n * DCAP + t], sv);
        if (MODE == 0) sv *= 0.1f;         // softmax of zeros over 10 capsules
        // squash over the 16 dims (lanes 0..15 of wave 0)
        float nq = sv * sv;
        #pragma unroll
        for (int mm = 8; mm >= 1; mm >>= 1) nq += __shfl_xor(nq, mm, 16);
        nq += 1e-7f;
        const float coeff = sqrtf(nq) / (1.0f + nq);
        const float v = coeff * sv;
        if (MODE == 2)
            dst[(size_t)(b * NCAP + n) * DCAP + t] = v;
        else
            vv[t] = v;
    }
    if (MODE != 2) {
        __syncthreads();
        float wd = 0.f;
        #pragma unroll
        for (int dd = 0; dd < DCAP; ++dd)
            wd = fmaf(W[t * (NCAP * DCAP) + n * DCAP + dd], vv[dd], wd);
        dst[(size_t)(b * NCAP + n) * DIN + t] = wd;
    }
}

// Routing pass: per position compute 10 logits u.w_n, softmax over n,
// then accumulate c[n] * u[b][i][:] into a per-(b,chunk) partial (no atomics).
// Each wave owns a tile of 64 positions; phase 1 lane-owns-position,
// phase 2 lane-owns-dim with shfl broadcast of c. w reads are wave-uniform
// -> scalar loads, no LDS in the hot loop; 4 waves reduce through LDS at end.
__global__ __launch_bounds__(256) void caps_route(const float* __restrict__ u,
                                                  const float* __restrict__ wsrc,
                                                  float* __restrict__ pdst) {
    const int b = blockIdx.x;
    const int chunk = blockIdx.y;          // 16
    const int wave = threadIdx.x >> 6;     // 4 waves
    const int lane = threadIdx.x & 63;
    const int tile = chunk * 4 + wave;     // 64 tiles of 64 positions
    const int pos0 = tile * 64;
    const float* wb = wsrc + (size_t)b * (NCAP * DIN);

    // ---- phase 1: logits + softmax (lane owns position pos0+lane) ----
    const float4* up = (const float4*)(u + ((size_t)b * NPOS + pos0 + lane) * DIN);
    float lg[NCAP];
    #pragma unroll
    for (int n = 0; n < NCAP; ++n) lg[n] = 0.f;
    #pragma unroll 4
    for (int k = 0; k < DIN / 4; ++k) {
        const float4 u4 = up[k];
        #pragma unroll
        for (int n = 0; n < NCAP; ++n) {
            const float4 w4 = ((const float4*)(wb + n * DIN))[k];  // uniform -> s_load
            lg[n] = fmaf(u4.x, w4.x,
                    fmaf(u4.y, w4.y,
                    fmaf(u4.z, w4.z,
                    fmaf(u4.w, w4.w, lg[n]))));
        }
    }
    float m = lg[0];
    #pragma unroll
    for (int n = 1; n < NCAP; ++n) m = fmaxf(m, lg[n]);
    float c[NCAP];
    float ssum = 0.f;
    #pragma unroll
    for (int n = 0; n < NCAP; ++n) { c[n] = __expf(lg[n] - m); ssum += c[n]; }
    const float inv = 1.0f / ssum;
    #pragma unroll
    for (int n = 0; n < NCAP; ++n) c[n] *= inv;

    // ---- phase 2: accumulate over this wave's 64 positions ----
    const float* ub = u + ((size_t)b * NPOS + pos0) * DIN;
    float acc0[NCAP], acc1[NCAP];
    #pragma unroll
    for (int n = 0; n < NCAP; ++n) { acc0[n] = 0.f; acc1[n] = 0.f; }
    for (int p = 0; p < 64; ++p) {
        const float u0 = ub[p * DIN + lane];        // coalesced, L1/L2-hot
        const float u1 = ub[p * DIN + lane + 64];
        #pragma unroll
        for (int n = 0; n < NCAP; ++n) {
            const float cp = __shfl(c[n], p, 64);   // uniform p -> v_readlane
            acc0[n] = fmaf(cp, u0, acc0[n]);
            acc1[n] = fmaf(cp, u1, acc1[n]);
        }
    }

    // ---- block reduction across 4 waves through LDS, then one store ----
    __shared__ float red[4][NCAP * DIN];            // 20.5 KB
    #pragma unroll
    for (int n = 0; n < NCAP; ++n) {
        red[wave][n * DIN + lane]      = acc0[n];
        red[wave][n * DIN + 64 + lane] = acc1[n];
    }
    __syncthreads();
    float* pb = pdst + ((size_t)(b * 16 + chunk) * NCAP) * DIN;
    for (int o = threadIdx.x; o < NCAP * DIN; o += 256) {
        pb[o] = red[0][o] + red[1][o] + red[2][o] + red[3][o];
    }
}

extern "C" void kernel_launch(void* const* d_in, const int* in_sizes, int n_in,
                              void* d_out, int out_size, void* d_ws, size_t ws_size,
                              hipStream_t stream) {
    const float* u = (const float*)d_in[0];   // [64][4096][128]
    const float* W = (const float*)d_in[1];   // [128][160]
    float* out = (float*)d_out;               // [64][10][16]
    float* ws = (float*)d_ws;

    float* partial = ws;                      // 131072 floats
    float* wbuf    = ws + 131072;             // 81920 floats
    float* pws     = ws + 212992;             // 1310720 floats (5.24 MB)

    caps_sum<<<dim3(NB, 16), 256, 0, stream>>>(u, partial);
    caps_small<0><<<NB * NCAP, 128, 0, stream>>>(partial, W, wbuf);   // v1 -> w1
    caps_route<<<dim3(NB, 16), 256, 0, stream>>>(u, wbuf, pws);       // iter 2 partials
    caps_small<1><<<NB * NCAP, 128, 0, stream>>>(pws, W, wbuf);       // v2 -> w2
    caps_route<<<dim3(NB, 16), 256, 0, stream>>>(u, wbuf, pws);       // iter 3 partials
    caps_small<2><<<NB * NCAP, 128, 0, stream>>>(pws, W, out);        // v3 -> out
}